// Round 7
// baseline (242.339 us; speedup 1.0000x reference)
//
#include <hip/hip_runtime.h>
#include <math.h>

// Problem shape (fixed by the reference): x = (B=4, S=8192, D=1024) float32.
// out[b,s,d] = x[b,s,d] + pos[s,d]
//   pos[s,d] = sin(s / 10000^((d+1)/D)) if d even, cos(...) if d odd.
#define PE_S 8192
#define PE_D 1024
#define PE_B 4

#define PE_K 8                                  // 1-KiB DMA chunks per wave-slot
#define PE_THREADS 256
#define PE_QTOTAL (PE_B * PE_S * PE_D / 4)      // 8,388,608 float4 quads
#define PE_NT (PE_QTOTAL / PE_K)                // 1,048,576 threads
#define PE_BLOCKS (PE_NT / PE_THREADS)          // 4096 blocks

typedef float f32x4 __attribute__((ext_vector_type(4)));

// Native-trig positional value (branch-free, single BB). v_sin/cos take
// REVOLUTIONS; wrev = 10000^-((j+1)/D) / (2pi) folds -log2(2pi) into one
// v_exp_f32. fmaf residual keeps the fract reduction effectively fp64;
// absmax has stayed 0.03125 across all rounds with this path.
__device__ __forceinline__ float pe_sin(float fs, float wrev) {
    float t = fs * wrev;
    float r = t - floorf(t);
    r += fmaf(fs, wrev, -t);            // exact product residual
    return __builtin_amdgcn_sinf(r);    // sin(2*pi*r)
}
__device__ __forceinline__ float pe_cos(float fs, float wrev) {
    float t = fs * wrev;
    float r = t - floorf(t);
    r += fmaf(fs, wrev, -t);
    return __builtin_amdgcn_cosf(r);    // cos(2*pi*r)
}

// ASYNC-DMA PIPELINE (global_load_lds). Rounds 1/3/4/5/6 all proved the
// machine scheduler re-sinks VGPR-destined loads to their use point (VGPR
// came back 24-32 every time), collapsing every source-level pipeline to
// load->wait->store per 1 KiB. global_load_lds sidesteps the heuristic
// entirely: the DMA holds NO VGPRs, so there is nothing to sink -- 8
// fire-and-forget 1-KiB loads are in flight per wave BY CONSTRUCTION.
//   wave timeline: issue 8 DMAs -> compute all 8 trig quads under the
//   flight -> ONE vmcnt(0) drain -> 8x {ds_read_b128, add, store}.
// Stores are all issued after the single drain: no store-ack ever gates a
// load (the r3 disease). LDS 32 KB/block -> 5 blocks/CU -> 20 waves/CU,
// 8 KiB outstanding reads per wave = ~160 KiB/CU (~6x the 6.3 TB/s
// latency-BW product). No nt: L3 serves ~half the x reads (FETCH=67MB).
// DMA lds-dest rule (m104): dest = wave-uniform base + lane*16, so lbase+
// k*256 (uniform) and the global per-lane addr (tid contiguous) match the
// linear layout exactly; ds_read at ln*16 reads it back, 2-way bank
// aliasing only (free per m136).
__global__ __launch_bounds__(PE_THREADS) void position_encoder_kernel(
    const float* __restrict__ x, float* __restrict__ out) {
    __shared__ __attribute__((aligned(16)))
        float lds[(PE_THREADS / 64) * PE_K * 256];   // 4 waves * 8 KiB

    const int tid = blockIdx.x * blockDim.x + threadIdx.x;  // 0..PE_NT-1
    const int wv  = threadIdx.x >> 6;                       // wave id (uniform)
    const int ln  = threadIdx.x & 63;
    const int d0  = (tid & (PE_D / 4 - 1)) << 2;            // constant/thread

    float* lbase = &lds[wv * (PE_K * 256)];

    // ---- issue all 8 async DMA loads (zero VGPR cost, cannot be sunk) ----
#pragma unroll
    for (int k = 0; k < PE_K; ++k) {
        const size_t goff = (size_t)(tid + k * PE_NT) * 4;  // per-lane gaddr
        __builtin_amdgcn_global_load_lds(
            (const __attribute__((address_space(1))) void*)(x + goff),
            (__attribute__((address_space(3))) void*)(lbase + k * 256),
            16, 0, 0);
    }

    // ---- all trig under the DMA flight (only s varies across chunks) ----
    const float A2 = -0.012976281620653760f;  // -log2(10000)/1024
    const float C  = -2.6514961294723187f;    // -log2(2*pi)
    const float w0 = exp2f(fmaf((float)(d0 + 1), A2, C));
    const float w1 = exp2f(fmaf((float)(d0 + 2), A2, C));
    const float w2 = exp2f(fmaf((float)(d0 + 3), A2, C));
    const float w3 = exp2f(fmaf((float)(d0 + 4), A2, C));

    f32x4 p[PE_K];                      // constant-indexed under full unroll
#pragma unroll
    for (int k = 0; k < PE_K; ++k) {
        const int q = tid + k * PE_NT;
        const float fs = (float)((q >> 8) & (PE_S - 1));
        p[k].x = pe_sin(fs, w0);        // d0   even -> sin
        p[k].y = pe_cos(fs, w1);        // d0+1 odd  -> cos
        p[k].z = pe_sin(fs, w2);        // d0+2 even -> sin
        p[k].w = pe_cos(fs, w3);        // d0+3 odd  -> cos
    }

    // ---- single drain of the 8 DMAs (no stores outstanding yet) ----
    __builtin_amdgcn_sched_barrier(0);
    __builtin_amdgcn_s_waitcnt(0x0f70);   // vmcnt(0), lgkm/exp unconstrained
    __builtin_amdgcn_sched_barrier(0);    // rule #18: nothing hoists above

    // ---- LDS -> add -> store (no vmem waits until endpgm) ----
#pragma unroll
    for (int k = 0; k < PE_K; ++k) {
        const size_t q = (size_t)tid + (size_t)k * PE_NT;
        const f32x4 v = *reinterpret_cast<const f32x4*>(&lbase[k * 256 + ln * 4]);
        *reinterpret_cast<f32x4*>(out + q * 4) = v + p[k];
    }
}

extern "C" void kernel_launch(void* const* d_in, const int* in_sizes, int n_in,
                              void* d_out, int out_size, void* d_ws, size_t ws_size,
                              hipStream_t stream) {
    const float* x = (const float*)d_in[0];
    float* out = (float*)d_out;
    position_encoder_kernel<<<PE_BLOCKS, PE_THREADS, 0, stream>>>(x, out);
}